// Round 7
// baseline (266.356 us; speedup 1.0000x reference)
//
#include <hip/hip_runtime.h>

// FP8 MLP, fully fused:  out = q(relu(q(x)@q(w1)^T)) @ q(w2)^T
// R7: 8-wave (512-thr) blocks @ __launch_bounds__(512,2) -> 256-VGPR budget,
// no spills (R4/R6's 42MB scratch WRITE_SIZE was the wall). M=128, CHUNK=512,
// grid=256 (1 block/CU). Wave tile 64dh x 128batch: acc = 8 x f32x16 = 128
// regs, 12 b128 LDS reads per 32 MFMAs (reuse 2.67). fc2: per-wave 16 rows x
// full 512 k, no reduction. Verified slot involution g^((row>>1)&3) on Bt/Xt;
// H b32-slot swizzle s^((row&15)<<1).

typedef float f32x4 __attribute__((ext_vector_type(4)));
typedef float f32x16 __attribute__((ext_vector_type(16)));

#define DIN 784
#define KP  832          // 13 * 64 (zero-padded K)
#define DH  4096
#define NKS 13
#define NCH 8
#define CHUNK 512
#define MROWS 128

__device__ __forceinline__ void gload_lds16(const void* g, void* l) {
  __builtin_amdgcn_global_load_lds(
      (const __attribute__((address_space(1))) unsigned int*)g,
      (__attribute__((address_space(3))) unsigned int*)l, 16, 0, 0);
}

__device__ __forceinline__ unsigned long long q8(float4 a, float4 b) {
  int lo = __builtin_amdgcn_cvt_pk_fp8_f32(a.x, a.y, 0, false);
  lo     = __builtin_amdgcn_cvt_pk_fp8_f32(a.z, a.w, lo, true);
  int hi = __builtin_amdgcn_cvt_pk_fp8_f32(b.x, b.y, 0, false);
  hi     = __builtin_amdgcn_cvt_pk_fp8_f32(b.z, b.w, hi, true);
  return (unsigned long long)(unsigned)lo |
         ((unsigned long long)(unsigned)hi << 32);
}

// ---- quantize row-major f32 [rows][784] -> fp8 [rows][KP], k-interleaved ----
// Row byte p = ks*64 + hi*32 + kk*8 + j holds q(src[row][ks*64 + kk*16 + hi*8 + j]).

__global__ __launch_bounds__(256) void quant_in_k(const float* __restrict__ src,
                                                  unsigned char* __restrict__ dst) {
  int idx = blockIdx.x * 256 + threadIdx.x;     // rows * 52 threads (exact)
  int row = idx / 52, g = idx % 52;
  int ks = g >> 2, q = g & 3;
  int k0 = ks * 64 + (q & 1) * 32 + (q >> 1) * 8;
  int k1 = k0 + 16;
  const float* r = src + (size_t)row * DIN;
  unsigned long long va = 0ull, vb = 0ull;
  if (k0 < DIN) va = q8(*(const float4*)(r + k0), *(const float4*)(r + k0 + 4));
  if (k1 < DIN) vb = q8(*(const float4*)(r + k1), *(const float4*)(r + k1 + 4));
  ulonglong2 v; v.x = va; v.y = vb;
  *(ulonglong2*)(dst + (size_t)row * KP + ks * 64 + q * 16) = v;
}

__global__ __launch_bounds__(256) void quant_w2_k(const float* __restrict__ w2,
                                                  unsigned char* __restrict__ w2q) {
  int idx = blockIdx.x * 256 + threadIdx.x;     // 16 rows * 256 chunks(16B)
  int r = idx >> 8, c = idx & 255;
  ulonglong2 v; v.x = 0ull; v.y = 0ull;
  if (r < 10) {
    const float* p = w2 + (size_t)r * DH + c * 16;
    v.x = q8(*(const float4*)(p), *(const float4*)(p + 4));
    v.y = q8(*(const float4*)(p + 8), *(const float4*)(p + 12));
  }
  *(ulonglong2*)(w2q + (size_t)r * DH + c * 16) = v;  // rows 10..15 = 0
}

// ------------------------------ fused MLP -----------------------------------

__global__ __launch_bounds__(512, 2)
void fused_mlp(const unsigned char* __restrict__ xq,
               const unsigned char* __restrict__ w1q,
               const unsigned char* __restrict__ w2q,
               float* __restrict__ out) {
  __shared__ unsigned char Bt[2][CHUNK * 64];   // 64 KB
  __shared__ unsigned char Xt[2][MROWS * 64];   // 16 KB
  __shared__ unsigned char H[MROWS * CHUNK];    // 64 KB

  const int tid = threadIdx.x;
  const int lane = tid & 63;
  const int w  = tid >> 6;          // wave 0..7 -> dh slice w*64
  const int l31 = lane & 31;
  const int hi  = lane >> 5;
  const long row0 = (long)blockIdx.x * MROWS;

  // per-lane staging offsets (invariant; bits1-2 of row unchanged by +t*128)
  const int sS = tid & 3;
  const int nS = tid >> 2;                       // 0..127
  const int gS = (sS ^ ((nS >> 1) & 3)) << 4;    // pre-swizzled source group
  const int w1off0 = (nS      ) * KP + gS;
  const int w1off1 = (nS + 128) * KP + gS;
  const int w1off2 = (nS + 256) * KP + gS;
  const int w1off3 = (nS + 384) * KP + gS;
  const int xoff   = (int)((row0 + nS) * KP) + gS;

#define STAGE(nch_, ks_, b_)                                                   \
  do {                                                                         \
    const unsigned char* wb_ = w1q + (size_t)(nch_) * CHUNK * KP + (ks_) * 64; \
    gload_lds16(wb_ + w1off0, &Bt[b_][tid * 16]);                              \
    gload_lds16(wb_ + w1off1, &Bt[b_][tid * 16 + 8192]);                       \
    gload_lds16(wb_ + w1off2, &Bt[b_][tid * 16 + 16384]);                      \
    gload_lds16(wb_ + w1off3, &Bt[b_][tid * 16 + 24576]);                      \
    gload_lds16(xq + xoff + (ks_) * 64, &Xt[b_][tid * 16]);                    \
  } while (0)

  // fragment read offsets: off(r, g) = r*64 + ((g ^ ((r>>1)&3))<<4)
#define SOFF(r_, g_) ((r_) * 64 + ((((g_) ^ (((r_) >> 1) & 3))) << 4))
  const int ar0 = w * 64 + l31, ar1 = ar0 + 32;
  const int br0 = l31, br1 = l31 + 32, br2 = l31 + 64, br3 = l31 + 96;
  const int pA0 = SOFF(ar0, 2 * hi),     pA1 = SOFF(ar1, 2 * hi);
  const int qA0 = SOFF(ar0, 2 * hi + 1), qA1 = SOFF(ar1, 2 * hi + 1);
  const int pB0 = SOFF(br0, 2 * hi),     pB1 = SOFF(br1, 2 * hi);
  const int pB2 = SOFF(br2, 2 * hi),     pB3 = SOFF(br3, 2 * hi);
  const int qB0 = SOFF(br0, 2 * hi + 1), qB1 = SOFF(br1, 2 * hi + 1);
  const int qB2 = SOFF(br2, 2 * hi + 1), qB3 = SOFF(br3, 2 * hi + 1);
#undef SOFF

  STAGE(0, 0, 0);
  asm volatile("s_waitcnt vmcnt(0)" ::: "memory");
  __syncthreads();

  f32x4 acc2 = {0.f, 0.f, 0.f, 0.f};
  int buf = 0;
  for (int nch = 0; nch < NCH; ++nch) {
    f32x16 a00 = {}, a01 = {}, a02 = {}, a03 = {};
    f32x16 a10 = {}, a11 = {}, a12 = {}, a13 = {};
#pragma unroll 1
    for (int ks = 0; ks < NKS; ++ks) {
      if (ks < NKS - 1)       STAGE(nch, ks + 1, buf ^ 1);
      else if (nch < NCH - 1) STAGE(nch + 1, 0, buf ^ 1);

#define PHASE(OA0, OA1, OB0, OB1, OB2, OB3)                                    \
      {                                                                        \
        ulonglong2 A0 = *(const ulonglong2*)&Bt[buf][OA0];                     \
        ulonglong2 A1 = *(const ulonglong2*)&Bt[buf][OA1];                     \
        ulonglong2 B0 = *(const ulonglong2*)&Xt[buf][OB0];                     \
        ulonglong2 B1 = *(const ulonglong2*)&Xt[buf][OB1];                     \
        ulonglong2 B2 = *(const ulonglong2*)&Xt[buf][OB2];                     \
        ulonglong2 B3 = *(const ulonglong2*)&Xt[buf][OB3];                     \
        __builtin_amdgcn_s_setprio(1);                                         \
        a00 = __builtin_amdgcn_mfma_f32_32x32x16_fp8_fp8((long)A0.x, (long)B0.x, a00, 0, 0, 0); \
        a01 = __builtin_amdgcn_mfma_f32_32x32x16_fp8_fp8((long)A0.x, (long)B1.x, a01, 0, 0, 0); \
        a02 = __builtin_amdgcn_mfma_f32_32x32x16_fp8_fp8((long)A0.x, (long)B2.x, a02, 0, 0, 0); \
        a03 = __builtin_amdgcn_mfma_f32_32x32x16_fp8_fp8((long)A0.x, (long)B3.x, a03, 0, 0, 0); \
        a10 = __builtin_amdgcn_mfma_f32_32x32x16_fp8_fp8((long)A1.x, (long)B0.x, a10, 0, 0, 0); \
        a11 = __builtin_amdgcn_mfma_f32_32x32x16_fp8_fp8((long)A1.x, (long)B1.x, a11, 0, 0, 0); \
        a12 = __builtin_amdgcn_mfma_f32_32x32x16_fp8_fp8((long)A1.x, (long)B2.x, a12, 0, 0, 0); \
        a13 = __builtin_amdgcn_mfma_f32_32x32x16_fp8_fp8((long)A1.x, (long)B3.x, a13, 0, 0, 0); \
        a00 = __builtin_amdgcn_mfma_f32_32x32x16_fp8_fp8((long)A0.y, (long)B0.y, a00, 0, 0, 0); \
        a01 = __builtin_amdgcn_mfma_f32_32x32x16_fp8_fp8((long)A0.y, (long)B1.y, a01, 0, 0, 0); \
        a02 = __builtin_amdgcn_mfma_f32_32x32x16_fp8_fp8((long)A0.y, (long)B2.y, a02, 0, 0, 0); \
        a03 = __builtin_amdgcn_mfma_f32_32x32x16_fp8_fp8((long)A0.y, (long)B3.y, a03, 0, 0, 0); \
        a10 = __builtin_amdgcn_mfma_f32_32x32x16_fp8_fp8((long)A1.y, (long)B0.y, a10, 0, 0, 0); \
        a11 = __builtin_amdgcn_mfma_f32_32x32x16_fp8_fp8((long)A1.y, (long)B1.y, a11, 0, 0, 0); \
        a12 = __builtin_amdgcn_mfma_f32_32x32x16_fp8_fp8((long)A1.y, (long)B2.y, a12, 0, 0, 0); \
        a13 = __builtin_amdgcn_mfma_f32_32x32x16_fp8_fp8((long)A1.y, (long)B3.y, a13, 0, 0, 0); \
        __builtin_amdgcn_s_setprio(0);                                         \
      }

      PHASE(pA0, pA1, pB0, pB1, pB2, pB3)          // k-slices 0,1
      __builtin_amdgcn_sched_barrier(0);
      PHASE(qA0, qA1, qB0, qB1, qB2, qB3)          // k-slices 2,3
#undef PHASE

      if (ks == NKS - 1) {
        // ---- relu + quantize -> H. D(32x32): col(batch)=l31,
        //      dh-in-frag = (reg&3) + 8*(reg>>2) + 4*hi ----
#define HWR(accv, rbv, dhb)                                                    \
        do {                                                                   \
          _Pragma("unroll") for (int qq = 0; qq < 4; ++qq) {                   \
            int dh_ = (dhb) + 8 * qq;                                          \
            unsigned wv = (unsigned)__builtin_amdgcn_cvt_pk_fp8_f32(           \
                fmaxf((accv)[4*qq+0], 0.f), fmaxf((accv)[4*qq+1], 0.f), 0, false); \
            wv = (unsigned)__builtin_amdgcn_cvt_pk_fp8_f32(                    \
                fmaxf((accv)[4*qq+2], 0.f), fmaxf((accv)[4*qq+3], 0.f), (int)wv, true); \
            int sp_ = (dh_ >> 2) ^ (((rbv) & 15) << 1);                        \
            *(unsigned int*)&H[(rbv) * CHUNK + sp_ * 4] = wv;                  \
          }                                                                    \
        } while (0)
        {
          const int dh0 = w * 64 + 4 * hi;        // ai=0
          const int dh1 = dh0 + 32;               // ai=1
          HWR(a00, br0, dh0); HWR(a01, br1, dh0);
          HWR(a02, br2, dh0); HWR(a03, br3, dh0);
          HWR(a10, br0, dh1); HWR(a11, br1, dh1);
          HWR(a12, br2, dh1); HWR(a13, br3, dh1);
        }
#undef HWR
        asm volatile("s_waitcnt lgkmcnt(0)" ::: "memory");
        __builtin_amdgcn_s_barrier();
        asm volatile("" ::: "memory");
        // ---- fc2: 16 MFMAs (16x16x32), wave w -> rows w*16..w*16+15 ----
        {
          const int r2 = w * 16 + (lane & 15);
          const int x2 = (lane & 15) << 1;
          const unsigned char* w2p = w2q + (size_t)(lane & 15) * DH + nch * CHUNK;
#pragma unroll
          for (int kk = 0; kk < 16; ++kk) {
            int dhl = kk * 32 + (lane >> 4) * 8;
            long a2 = *(const long long*)&H[r2 * CHUNK + ((((dhl >> 2) ^ x2)) << 2)];
            long b2 = *(const long long*)(w2p + dhl);
            acc2 = __builtin_amdgcn_mfma_f32_16x16x32_fp8_fp8(a2, b2, acc2, 0, 0, 0);
          }
        }
      }

      asm volatile("s_waitcnt vmcnt(0)" ::: "memory");
      __builtin_amdgcn_s_barrier();
      asm volatile("" ::: "memory");
      buf ^= 1;
    }
  }

  // ---- store out[128][10]: wave w rows w*16.., col = lane&15 ----
  if ((lane & 15) < 10) {
#pragma unroll
    for (int j = 0; j < 4; ++j) {
      int rl = w * 16 + (lane >> 4) * 4 + j;
      out[(row0 + rl) * 10 + (lane & 15)] = acc2[j];
    }
  }
#undef STAGE
}

extern "C" void kernel_launch(void* const* d_in, const int* in_sizes, int n_in,
                              void* d_out, int out_size, void* d_ws, size_t ws_size,
                              hipStream_t stream) {
  const float* x  = (const float*)d_in[0];
  const float* w1 = (const float*)d_in[1];
  const float* w2 = (const float*)d_in[2];
  float* out = (float*)d_out;

  unsigned char* w1q = (unsigned char*)d_ws;              // [4096][832]
  unsigned char* w2q = w1q + (size_t)DH * KP;             // [16][4096]
  unsigned char* xq  = w2q + (size_t)16 * DH;             // [32768][832]

  quant_in_k<<<(DH * 52) / 256, 256, 0, stream>>>(w1, w1q);
  quant_w2_k<<<16, 256, 0, stream>>>(w2, w2q);
  quant_in_k<<<(32768 * 52) / 256, 256, 0, stream>>>(x, xq);
  fused_mlp<<<256, 512, 0, stream>>>(xq, w1q, w2q, out);
}